// Round 1
// 284.310 us; speedup vs baseline: 1.0241x; 1.0241x over previous
//
#include <hip/hip_runtime.h>
#include <stdint.h>

// ---------------------------------------------------------------------------
// NIVR: coord-MLP over 512x512 grid.
//   pre0_kernel: time branch once -> tvec[512] (was recomputed by all 512
//                coord blocks = ~45us of redundant work).
//   pre1_kernel: posenc tables Txp (=Tx+tvec), Ty; W2f -> bf16 W2s.
//   main: h1 = relu(Txp[x]+Ty[y]); layer2 via MFMA bf16 16x16x32 with
//         SWAPPED operands (D = W2^T h1^T = h2^T) so the layer-3 k-dim
//         lands on (q,r) in-register; epilogue = 48 FMA + 24 shfl per wave
//         (was 192 FMA + 192 shfl). Output [3][N].
//
// R10 vs R9 theory: main_kernel is DS-pipe bound (A-frag re-reads 99k cyc/CU
// vs 40k matrix) with big side-costs: epilogue shfl tree (~50-140k cyc/CU on
// the same DS pipe), fill f2bf VALU (~95k cyc/CU), and a 60us pre_kernel that
// recomputes tvec 512x. R10 removes the three side-costs, K-loop untouched:
//  - operand swap is free (A/B frag index functions are identical; only acc
//    layout changes: acc[mt][nt][r] = h2[pix=mt*16+lr][col=w*64+nt*16+q*4+r]).
//  - fill uses v_cvt_pk_bf16_f32 (4 insts vs ~32 for manual RNE).
// ---------------------------------------------------------------------------

typedef short bf16x8 __attribute__((ext_vector_type(8)));
typedef float f32x4 __attribute__((ext_vector_type(4)));

#define PI_F 3.14159265358979323846f
#define SIDE 512
#define NPIX (SIDE * SIDE)

__device__ __forceinline__ unsigned short f2bf(float f) {
  unsigned int u = __float_as_uint(f);
  u += 0x7fffu + ((u >> 16) & 1u);
  return (unsigned short)(u >> 16);
}

// ---------------------------------------------------------------------------
// pre0: ONE block, 512 threads. Time branch -> tvec[k] = b1f[k] + phi @ W1f
// rows 40..167. ~3us.
// ---------------------------------------------------------------------------
__global__ void pre0_kernel(const float* __restrict__ W1p, const float* __restrict__ b1p,
                            const float* __restrict__ W2p, const float* __restrict__ b2p,
                            const float* __restrict__ W1f, const float* __restrict__ b1f,
                            const int* __restrict__ idx, float* __restrict__ tvec) {
  __shared__ float r_s[32];
  __shared__ float h_s[256];
  __shared__ float phi_s[128];
  const int t = threadIdx.x;
  if (t < 16) {
    float tt = (float)idx[0] / 300.0f;
    float ang = tt * ldexpf(PI_F, t);
    r_s[t] = sinf(ang);
    r_s[16 + t] = cosf(ang);
  }
  __syncthreads();
  if (t < 256) {
    float a = b1p[t];
#pragma unroll
    for (int i = 0; i < 32; ++i) a += r_s[i] * W1p[i * 256 + t];
    h_s[t] = fmaxf(a, 0.f);
  }
  __syncthreads();
  if (t < 128) {
    float a = b2p[t];
    for (int i = 0; i < 256; ++i) a += h_s[i] * W2p[i * 128 + t];
    phi_s[t] = a;
  }
  __syncthreads();
  {
    float tv = b1f[t];
    for (int p = 0; p < 128; ++p) tv += phi_s[p] * W1f[(40 + p) * 512 + t];
    tvec[t] = tv;
  }
}

// ---------------------------------------------------------------------------
// pre1: 1024 blocks x 512 threads.
//   blocks 0..511  : Txp[v][k] = tvec[k] + sum_l enc[l] W1f[l][k]
//                    Ty [v][k] =           sum_l enc[l] W1f[20+l][k]
//   blocks 512..1023: W2f -> bf16 frag-swizzled W2s (k-row = b-512)
// W2s layout: id = ks*16384 + nt*512 + q*128 + ni*8 + j  (shorts)
//   W2s[id] = bf16(W2f[ks*32 + q*8 + j][nt*16 + ni])
// ---------------------------------------------------------------------------
__global__ void pre1_kernel(const float* __restrict__ W1f, const float* __restrict__ W2f,
                            const float* __restrict__ tvec,
                            float* __restrict__ Txp, float* __restrict__ Ty,
                            unsigned short* __restrict__ W2s) {
  const int b = blockIdx.x;
  const int t = threadIdx.x;

  if (b >= 512) {
    const int k = b - 512, n = t;
    const int ks = k >> 5, q = (k >> 3) & 3, j = k & 7;
    const int nt = n >> 4, ni = n & 15;
    W2s[ks * 16384 + nt * 512 + q * 128 + ni * 8 + j] = f2bf(W2f[k * 512 + n]);
    return;
  }

  __shared__ float enc[20];
  if (t < 10) {
    float u = (float)b / 512.0f;
    float ang = u * ldexpf(PI_F, t);
    enc[t] = sinf(ang);
    enc[10 + t] = cosf(ang);
  }
  __syncthreads();
  {
    float ax = tvec[t], ay = 0.f;
#pragma unroll
    for (int l = 0; l < 20; ++l) {
      ax += enc[l] * W1f[l * 512 + t];
      ay += enc[l] * W1f[(20 + l) * 512 + t];
    }
    Txp[b * 512 + t] = ax;
    Ty[b * 512 + t] = ay;
  }
}

// ---------------------------------------------------------------------------
// Main fused kernel. Block = 512 thr (8 waves), BM=64 (8x8 patch), BN=512,
// K=512 in 16 steps of 32. Wave w owns N-slice [w*64, w*64+64).
// A tile 64KB resident in LDS (filled once); B via depth-2 register pipeline.
// MFMA operands swapped: acc[mt][nt] holds h2^T fragments (see header).
// ---------------------------------------------------------------------------
__global__ __launch_bounds__(512, 2) void main_kernel(
    const float* __restrict__ Txp, const float* __restrict__ Ty,
    const unsigned short* __restrict__ W2s, const float* __restrict__ b2f,
    const float* __restrict__ W3f, const float* __restrict__ b3f,
    float* __restrict__ out) {
  __shared__ __attribute__((aligned(16))) unsigned short Ab[16 * 2048];  // 64KB
  __shared__ float part[8][64][3];                                       // 6KB

  const int t = threadIdx.x;
  const int w = t >> 6;            // wave id 0..7  (N-slice)
  const int lane = t & 63;
  const int q = lane >> 4;
  const int lr = lane & 15;
  const int x0 = blockIdx.x * 8, y0 = blockIdx.y * 8;

  // B: wave w owns nt-slots w*4..w*4+3; frag (ks,nt) at +ks*16384 + nt*512;
  // lane reads at +lane*8 (16B, coalesced 1KB/wave).
  const unsigned short* bptr = W2s + (w * 4) * 512 + lane * 8;

  // ---- B pipeline: depth 2. breg[ks%3] used at step ks. ----
  bf16x8 breg[3][4];
#pragma unroll
  for (int nt = 0; nt < 4; ++nt) {
    breg[0][nt] = *(const bf16x8*)(bptr + 0 * 16384 + nt * 512);
    breg[1][nt] = *(const bf16x8*)(bptr + 1 * 16384 + nt * 512);
  }

  // ---- A fill (once): thread (p = t>>3, s = t&7) covers pixel p,
  // k = ks*32 + s*4..+3; frag slot abase, conflict-free (R5-verified).
  // bf16 conversion via packed v_cvt_pk_bf16_f32 (RNE, 1 inst per 2 elems).
  {
    const int p = t >> 3, s = t & 7;
    const int xi = x0 + (p >> 3), yi = y0 + (p & 7);
    const float* txp = Txp + xi * 512 + s * 4;
    const float* typ = Ty + yi * 512 + s * 4;
    const int abase = (((p >> 4) * 4 + (s >> 1)) * 16 + (p & 15)) * 8 + (s & 1) * 4;
#pragma unroll
    for (int ks = 0; ks < 16; ++ks) {
      float4 a = *(const float4*)(txp + ks * 32);
      float4 b = *(const float4*)(typ + ks * 32);
      float v0 = fmaxf(a.x + b.x, 0.f);
      float v1 = fmaxf(a.y + b.y, 0.f);
      float v2 = fmaxf(a.z + b.z, 0.f);
      float v3 = fmaxf(a.w + b.w, 0.f);
      uint2 pk;
      asm("v_cvt_pk_bf16_f32 %0, %1, %2" : "=v"(pk.x) : "v"(v0), "v"(v1));
      asm("v_cvt_pk_bf16_f32 %0, %1, %2" : "=v"(pk.y) : "v"(v2), "v"(v3));
      *(uint2*)&Ab[ks * 2048 + abase] = pk;
    }
  }

  f32x4 acc[4][4];
#pragma unroll
  for (int i = 0; i < 4; ++i)
#pragma unroll
    for (int j2 = 0; j2 < 4; ++j2) acc[i][j2] = (f32x4){0.f, 0.f, 0.f, 0.f};

  __syncthreads();  // publishes A; the only barrier before the epilogue

  // ---- A-frag pipeline: depth 1. areg[ks&1] used at step ks. ----
  bf16x8 areg[2][4];
#pragma unroll
  for (int mt = 0; mt < 4; ++mt)
    areg[0][mt] = *(const bf16x8*)&Ab[0 * 2048 + mt * 512 + lane * 8];

  // ---- K-loop, fully unrolled, no barriers, no register copies ----
#pragma unroll
  for (int ks = 0; ks < 16; ++ks) {
    // B loads for step ks+2 (depth 2: ~2 step-walls of latency cover)
    if (ks + 2 < 16) {
#pragma unroll
      for (int nt = 0; nt < 4; ++nt)
        breg[(ks + 2) % 3][nt] =
            *(const bf16x8*)(bptr + (ks + 2) * 16384 + nt * 512);
    }
    // A-frag ds_reads for step ks+1 (issued before this step's MFMAs)
    if (ks + 1 < 16) {
#pragma unroll
      for (int mt = 0; mt < 4; ++mt)
        areg[(ks + 1) & 1][mt] =
            *(const bf16x8*)&Ab[(ks + 1) * 2048 + mt * 512 + lane * 8];
    }
    // MFMAs for step ks -- OPERANDS SWAPPED: D = W2slice^T x h1slice^T.
    // acc[mt][nt][r] = h2[pix = mt*16 + lr][col = w*64 + nt*16 + q*4 + r]
#pragma unroll
    for (int nt = 0; nt < 4; ++nt)
#pragma unroll
      for (int mt = 0; mt < 4; ++mt)
        acc[mt][nt] = __builtin_amdgcn_mfma_f32_16x16x32_bf16(
            breg[ks % 3][nt], areg[ks & 1][mt], acc[mt][nt], 0, 0, 0);
  }

  // ---- epilogue: h2 = relu(acc + b2f); rgb partial = h2 @ W3f.
  // Layer-3 k-dim (col) lives on (q,r) in-register -> 48 FMAs + reduce over
  // q only (shfl_xor 16,32 = 24 shuffles/wave; was 192). ----
  {
    float bb2[4][4];
    float w3v[4][4][3];
#pragma unroll
    for (int nt = 0; nt < 4; ++nt) {
      const int k0 = w * 64 + nt * 16 + q * 4;
      float4 bv = *(const float4*)&b2f[k0];
      bb2[nt][0] = bv.x; bb2[nt][1] = bv.y; bb2[nt][2] = bv.z; bb2[nt][3] = bv.w;
      float4 u0 = *(const float4*)&W3f[k0 * 3 + 0];
      float4 u1 = *(const float4*)&W3f[k0 * 3 + 4];
      float4 u2 = *(const float4*)&W3f[k0 * 3 + 8];
      w3v[nt][0][0] = u0.x; w3v[nt][0][1] = u0.y; w3v[nt][0][2] = u0.z;
      w3v[nt][1][0] = u0.w; w3v[nt][1][1] = u1.x; w3v[nt][1][2] = u1.y;
      w3v[nt][2][0] = u1.z; w3v[nt][2][1] = u1.w; w3v[nt][2][2] = u2.x;
      w3v[nt][3][0] = u2.y; w3v[nt][3][1] = u2.z; w3v[nt][3][2] = u2.w;
    }
    float p3[4][3];
#pragma unroll
    for (int mt = 0; mt < 4; ++mt) {
      p3[mt][0] = 0.f; p3[mt][1] = 0.f; p3[mt][2] = 0.f;
    }
#pragma unroll
    for (int mt = 0; mt < 4; ++mt)
#pragma unroll
      for (int nt = 0; nt < 4; ++nt)
#pragma unroll
        for (int r = 0; r < 4; ++r) {
          float h2 = fmaxf(acc[mt][nt][r] + bb2[nt][r], 0.f);
          p3[mt][0] += h2 * w3v[nt][r][0];
          p3[mt][1] += h2 * w3v[nt][r][1];
          p3[mt][2] += h2 * w3v[nt][r][2];
        }
    // reduce partial over q (lanes l, l^16, l^32, l^48)
#pragma unroll
    for (int d = 16; d < 64; d <<= 1)
#pragma unroll
      for (int mt = 0; mt < 4; ++mt)
#pragma unroll
        for (int cc = 0; cc < 3; ++cc)
          p3[mt][cc] += __shfl_xor(p3[mt][cc], d, 64);
    if (q < 3) {
#pragma unroll
      for (int mt = 0; mt < 4; ++mt) part[w][mt * 16 + lr][q] = p3[mt][q];
    }
  }
  __syncthreads();
  if (t < 192) {
    const int c = t >> 6, mm = t & 63;
    float sum = b3f[c];
#pragma unroll
    for (int ww = 0; ww < 8; ++ww) sum += part[ww][mm][c];
    const int n = (x0 + (mm >> 3)) * 512 + (y0 + (mm & 7));
    out[c * NPIX + n] = sum;
  }
}

// ---------------------------------------------------------------------------
// Inputs: 0 coords (unused), 1 W1p, 2 b1p, 3 W2p, 4 b2p, 5 W1f, 6 b1f,
//         7 W2f, 8 b2f, 9 W3f, 10 b3f, 11 idx
// ---------------------------------------------------------------------------
extern "C" void kernel_launch(void* const* d_in, const int* in_sizes, int n_in,
                              void* d_out, int out_size, void* d_ws, size_t ws_size,
                              hipStream_t stream) {
  const float* W1p = (const float*)d_in[1];
  const float* b1p = (const float*)d_in[2];
  const float* W2p = (const float*)d_in[3];
  const float* b2p = (const float*)d_in[4];
  const float* W1f = (const float*)d_in[5];
  const float* b1f = (const float*)d_in[6];
  const float* W2f = (const float*)d_in[7];
  const float* b2f = (const float*)d_in[8];
  const float* W3f = (const float*)d_in[9];
  const float* b3f = (const float*)d_in[10];
  const int* idx = (const int*)d_in[11];
  float* out = (float*)d_out;

  char* ws = (char*)d_ws;
  float* Txp = (float*)ws;                                   // 1 MB
  float* Ty = (float*)(ws + (1u << 20));                     // 1 MB
  unsigned short* W2s = (unsigned short*)(ws + (2u << 20));  // 512 KB
  float* tvec = (float*)(ws + (2u << 20) + (512u << 10));    // 2 KB

  hipLaunchKernelGGL(pre0_kernel, dim3(1), dim3(512), 0, stream,
                     W1p, b1p, W2p, b2p, W1f, b1f, idx, tvec);
  hipLaunchKernelGGL(pre1_kernel, dim3(1024), dim3(512), 0, stream,
                     W1f, W2f, tvec, Txp, Ty, W2s);
  hipLaunchKernelGGL(main_kernel, dim3(64, 64), dim3(512), 0, stream,
                     Txp, Ty, W2s, b2f, W3f, b3f, out);
}

// Round 2
// 241.754 us; speedup vs baseline: 1.2044x; 1.1760x over previous
//
#include <hip/hip_runtime.h>
#include <stdint.h>

// ---------------------------------------------------------------------------
// NIVR: coord-MLP over 512x512 grid.
//   pre0_kernel: time branch once -> tvec[512].
//   pre1_kernel: posenc tables Txp (=Tx+tvec), Ty; W2f -> bf16 W2s.
//   main: h1 = relu(Txp[x]+Ty[y]); layer2 via MFMA bf16 16x16x32 (swapped
//         operands => acc holds h2^T); fused layer3 epilogue. Output [3][N].
//
// R11 vs R10: counters showed latency-bound at 1 block/CU (Occupancy 22.6%
// = 2 waves/SIMD). Cause: unified VGPR+AGPR file; old live set acc(64A) +
// breg[3][4](48) + areg[2][4](32) + misc ~ 170 combined regs => 2 waves/SIMD
// => one 8-wave block/CU. R11 fits 128 combined regs for 2 blocks/CU:
//  - __launch_bounds__(512, 4): combined reg cap 128.
//  - breg depth 2 (32 regs), prefetch 1 step ahead (wall ~1k cyc >= L2 lat).
//  - areg: no prefetch, 4 ds_read_b128 at use (16 regs; ~120cyc covered by
//    3 sibling waves/SIMD).
//  - epilogue streamed per-nt: peak ~96 regs (was 140 => spill risk).
// Live: 64 acc + 32 breg + 16 areg + ~16 misc = 128. LDS 70KB x2 = 140 <= 160.
// ---------------------------------------------------------------------------

typedef short bf16x8 __attribute__((ext_vector_type(8)));
typedef float f32x4 __attribute__((ext_vector_type(4)));

#define PI_F 3.14159265358979323846f
#define SIDE 512
#define NPIX (SIDE * SIDE)

__device__ __forceinline__ unsigned short f2bf(float f) {
  unsigned int u = __float_as_uint(f);
  u += 0x7fffu + ((u >> 16) & 1u);
  return (unsigned short)(u >> 16);
}

// ---------------------------------------------------------------------------
// pre0: ONE block, 512 threads. Time branch -> tvec[k] = b1f[k] + phi @ W1f
// rows 40..167.
// ---------------------------------------------------------------------------
__global__ void pre0_kernel(const float* __restrict__ W1p, const float* __restrict__ b1p,
                            const float* __restrict__ W2p, const float* __restrict__ b2p,
                            const float* __restrict__ W1f, const float* __restrict__ b1f,
                            const int* __restrict__ idx, float* __restrict__ tvec) {
  __shared__ float r_s[32];
  __shared__ float h_s[256];
  __shared__ float phi_s[128];
  const int t = threadIdx.x;
  if (t < 16) {
    float tt = (float)idx[0] / 300.0f;
    float ang = tt * ldexpf(PI_F, t);
    r_s[t] = sinf(ang);
    r_s[16 + t] = cosf(ang);
  }
  __syncthreads();
  if (t < 256) {
    float a = b1p[t];
#pragma unroll
    for (int i = 0; i < 32; ++i) a += r_s[i] * W1p[i * 256 + t];
    h_s[t] = fmaxf(a, 0.f);
  }
  __syncthreads();
  if (t < 128) {
    float a = b2p[t];
    for (int i = 0; i < 256; ++i) a += h_s[i] * W2p[i * 128 + t];
    phi_s[t] = a;
  }
  __syncthreads();
  {
    float tv = b1f[t];
    for (int p = 0; p < 128; ++p) tv += phi_s[p] * W1f[(40 + p) * 512 + t];
    tvec[t] = tv;
  }
}

// ---------------------------------------------------------------------------
// pre1: 1024 blocks x 512 threads.
//   blocks 0..511  : Txp[v][k] = tvec[k] + sum_l enc[l] W1f[l][k]
//                    Ty [v][k] =           sum_l enc[l] W1f[20+l][k]
//   blocks 512..1023: W2f -> bf16 frag-swizzled W2s (k-row = b-512)
// W2s layout: id = ks*16384 + nt*512 + q*128 + ni*8 + j  (shorts)
//   W2s[id] = bf16(W2f[ks*32 + q*8 + j][nt*16 + ni])
// ---------------------------------------------------------------------------
__global__ void pre1_kernel(const float* __restrict__ W1f, const float* __restrict__ W2f,
                            const float* __restrict__ tvec,
                            float* __restrict__ Txp, float* __restrict__ Ty,
                            unsigned short* __restrict__ W2s) {
  const int b = blockIdx.x;
  const int t = threadIdx.x;

  if (b >= 512) {
    const int k = b - 512, n = t;
    const int ks = k >> 5, q = (k >> 3) & 3, j = k & 7;
    const int nt = n >> 4, ni = n & 15;
    W2s[ks * 16384 + nt * 512 + q * 128 + ni * 8 + j] = f2bf(W2f[k * 512 + n]);
    return;
  }

  __shared__ float enc[20];
  if (t < 10) {
    float u = (float)b / 512.0f;
    float ang = u * ldexpf(PI_F, t);
    enc[t] = sinf(ang);
    enc[10 + t] = cosf(ang);
  }
  __syncthreads();
  {
    float ax = tvec[t], ay = 0.f;
#pragma unroll
    for (int l = 0; l < 20; ++l) {
      ax += enc[l] * W1f[l * 512 + t];
      ay += enc[l] * W1f[(20 + l) * 512 + t];
    }
    Txp[b * 512 + t] = ax;
    Ty[b * 512 + t] = ay;
  }
}

// ---------------------------------------------------------------------------
// Main fused kernel. Block = 512 thr (8 waves), BM=64 (8x8 patch), BN=512,
// K=512 in 16 steps of 32. Wave w owns N-slice [w*64, w*64+64).
// A tile 64KB resident in LDS (filled once); B via depth-1 register prefetch.
// MFMA operands swapped: acc[mt][nt][r] = h2[pix=mt*16+lr][col=w*64+nt*16+q*4+r]
// ---------------------------------------------------------------------------
__global__ __launch_bounds__(512, 4) void main_kernel(
    const float* __restrict__ Txp, const float* __restrict__ Ty,
    const unsigned short* __restrict__ W2s, const float* __restrict__ b2f,
    const float* __restrict__ W3f, const float* __restrict__ b3f,
    float* __restrict__ out) {
  __shared__ __attribute__((aligned(16))) unsigned short Ab[16 * 2048];  // 64KB
  __shared__ float part[8][64][3];                                       // 6KB

  const int t = threadIdx.x;
  const int w = t >> 6;            // wave id 0..7  (N-slice)
  const int lane = t & 63;
  const int q = lane >> 4;
  const int lr = lane & 15;
  const int x0 = blockIdx.x * 8, y0 = blockIdx.y * 8;

  // B: wave w owns nt-slots w*4..w*4+3; frag (ks,nt) at +ks*16384 + nt*512;
  // lane reads at +lane*8 (16B, coalesced 1KB/wave).
  const unsigned short* bptr = W2s + (w * 4) * 512 + lane * 8;

  // ---- B pipeline: depth 1 (2 buffers). breg[ks&1] used at step ks. ----
  bf16x8 breg[2][4];
#pragma unroll
  for (int nt = 0; nt < 4; ++nt)
    breg[0][nt] = *(const bf16x8*)(bptr + 0 * 16384 + nt * 512);

  // ---- A fill (once): thread (p = t>>3, s = t&7) covers pixel p,
  // k = ks*32 + s*4..+3; frag slot abase, conflict-free (R5-verified).
  // bf16 conversion via packed v_cvt_pk_bf16_f32 (RNE).
  {
    const int p = t >> 3, s = t & 7;
    const int xi = x0 + (p >> 3), yi = y0 + (p & 7);
    const float* txp = Txp + xi * 512 + s * 4;
    const float* typ = Ty + yi * 512 + s * 4;
    const int abase = (((p >> 4) * 4 + (s >> 1)) * 16 + (p & 15)) * 8 + (s & 1) * 4;
#pragma unroll
    for (int ks = 0; ks < 16; ++ks) {
      float4 a = *(const float4*)(txp + ks * 32);
      float4 b = *(const float4*)(typ + ks * 32);
      float v0 = fmaxf(a.x + b.x, 0.f);
      float v1 = fmaxf(a.y + b.y, 0.f);
      float v2 = fmaxf(a.z + b.z, 0.f);
      float v3 = fmaxf(a.w + b.w, 0.f);
      uint2 pk;
      asm("v_cvt_pk_bf16_f32 %0, %1, %2" : "=v"(pk.x) : "v"(v0), "v"(v1));
      asm("v_cvt_pk_bf16_f32 %0, %1, %2" : "=v"(pk.y) : "v"(v2), "v"(v3));
      *(uint2*)&Ab[ks * 2048 + abase] = pk;
    }
  }

  f32x4 acc[4][4];
#pragma unroll
  for (int i = 0; i < 4; ++i)
#pragma unroll
    for (int j2 = 0; j2 < 4; ++j2) acc[i][j2] = (f32x4){0.f, 0.f, 0.f, 0.f};

  __syncthreads();  // publishes A; the only barrier before the epilogue

  // ---- K-loop, fully unrolled, no barriers, no register copies ----
#pragma unroll
  for (int ks = 0; ks < 16; ++ks) {
    // B loads for step ks+1 (issued before this step's MFMAs)
    if (ks + 1 < 16) {
#pragma unroll
      for (int nt = 0; nt < 4; ++nt)
        breg[(ks + 1) & 1][nt] =
            *(const bf16x8*)(bptr + (ks + 1) * 16384 + nt * 512);
    }
    // A-frags for this step: 4 ds_read_b128 at use (fresh regs each step)
    bf16x8 a0 = *(const bf16x8*)&Ab[ks * 2048 + 0 * 512 + lane * 8];
    bf16x8 a1 = *(const bf16x8*)&Ab[ks * 2048 + 1 * 512 + lane * 8];
    bf16x8 a2 = *(const bf16x8*)&Ab[ks * 2048 + 2 * 512 + lane * 8];
    bf16x8 a3 = *(const bf16x8*)&Ab[ks * 2048 + 3 * 512 + lane * 8];
    // MFMAs for step ks -- OPERANDS SWAPPED: D = W2slice^T x h1slice^T.
#pragma unroll
    for (int nt = 0; nt < 4; ++nt) {
      acc[0][nt] = __builtin_amdgcn_mfma_f32_16x16x32_bf16(
          breg[ks & 1][nt], a0, acc[0][nt], 0, 0, 0);
      acc[1][nt] = __builtin_amdgcn_mfma_f32_16x16x32_bf16(
          breg[ks & 1][nt], a1, acc[1][nt], 0, 0, 0);
      acc[2][nt] = __builtin_amdgcn_mfma_f32_16x16x32_bf16(
          breg[ks & 1][nt], a2, acc[2][nt], 0, 0, 0);
      acc[3][nt] = __builtin_amdgcn_mfma_f32_16x16x32_bf16(
          breg[ks & 1][nt], a3, acc[3][nt], 0, 0, 0);
    }
  }

  // ---- epilogue: h2 = relu(acc + b2f); rgb partial = h2 @ W3f.
  // Layer-3 k-dim (col) lives on (q,r) in-register; streamed per-nt to keep
  // peak register pressure ~96. Reduce over q via shfl_xor 16,32. ----
  {
    float p3[4][3];
#pragma unroll
    for (int mt = 0; mt < 4; ++mt) {
      p3[mt][0] = 0.f; p3[mt][1] = 0.f; p3[mt][2] = 0.f;
    }
#pragma unroll
    for (int nt = 0; nt < 4; ++nt) {
      const int k0 = w * 64 + nt * 16 + q * 4;
      float4 bv = *(const float4*)&b2f[k0];
      float bb[4] = {bv.x, bv.y, bv.z, bv.w};
      float4 u0 = *(const float4*)&W3f[k0 * 3 + 0];
      float4 u1 = *(const float4*)&W3f[k0 * 3 + 4];
      float4 u2 = *(const float4*)&W3f[k0 * 3 + 8];
      float wv[4][3];
      wv[0][0] = u0.x; wv[0][1] = u0.y; wv[0][2] = u0.z;
      wv[1][0] = u0.w; wv[1][1] = u1.x; wv[1][2] = u1.y;
      wv[2][0] = u1.z; wv[2][1] = u1.w; wv[2][2] = u2.x;
      wv[3][0] = u2.y; wv[3][1] = u2.z; wv[3][2] = u2.w;
#pragma unroll
      for (int mt = 0; mt < 4; ++mt)
#pragma unroll
        for (int r = 0; r < 4; ++r) {
          float h2 = fmaxf(acc[mt][nt][r] + bb[r], 0.f);
          p3[mt][0] += h2 * wv[r][0];
          p3[mt][1] += h2 * wv[r][1];
          p3[mt][2] += h2 * wv[r][2];
        }
    }
    // reduce partial over q (lanes l, l^16, l^32, l^48)
#pragma unroll
    for (int d = 16; d < 64; d <<= 1)
#pragma unroll
      for (int mt = 0; mt < 4; ++mt)
#pragma unroll
        for (int cc = 0; cc < 3; ++cc)
          p3[mt][cc] += __shfl_xor(p3[mt][cc], d, 64);
    if (q < 3) {
#pragma unroll
      for (int mt = 0; mt < 4; ++mt) part[w][mt * 16 + lr][q] = p3[mt][q];
    }
  }
  __syncthreads();
  if (t < 192) {
    const int c = t >> 6, mm = t & 63;
    float sum = b3f[c];
#pragma unroll
    for (int ww = 0; ww < 8; ++ww) sum += part[ww][mm][c];
    const int n = (x0 + (mm >> 3)) * 512 + (y0 + (mm & 7));
    out[c * NPIX + n] = sum;
  }
}

// ---------------------------------------------------------------------------
// Inputs: 0 coords (unused), 1 W1p, 2 b1p, 3 W2p, 4 b2p, 5 W1f, 6 b1f,
//         7 W2f, 8 b2f, 9 W3f, 10 b3f, 11 idx
// ---------------------------------------------------------------------------
extern "C" void kernel_launch(void* const* d_in, const int* in_sizes, int n_in,
                              void* d_out, int out_size, void* d_ws, size_t ws_size,
                              hipStream_t stream) {
  const float* W1p = (const float*)d_in[1];
  const float* b1p = (const float*)d_in[2];
  const float* W2p = (const float*)d_in[3];
  const float* b2p = (const float*)d_in[4];
  const float* W1f = (const float*)d_in[5];
  const float* b1f = (const float*)d_in[6];
  const float* W2f = (const float*)d_in[7];
  const float* b2f = (const float*)d_in[8];
  const float* W3f = (const float*)d_in[9];
  const float* b3f = (const float*)d_in[10];
  const int* idx = (const int*)d_in[11];
  float* out = (float*)d_out;

  char* ws = (char*)d_ws;
  float* Txp = (float*)ws;                                   // 1 MB
  float* Ty = (float*)(ws + (1u << 20));                     // 1 MB
  unsigned short* W2s = (unsigned short*)(ws + (2u << 20));  // 512 KB
  float* tvec = (float*)(ws + (2u << 20) + (512u << 10));    // 2 KB

  hipLaunchKernelGGL(pre0_kernel, dim3(1), dim3(512), 0, stream,
                     W1p, b1p, W2p, b2p, W1f, b1f, idx, tvec);
  hipLaunchKernelGGL(pre1_kernel, dim3(1024), dim3(512), 0, stream,
                     W1f, W2f, tvec, Txp, Ty, W2s);
  hipLaunchKernelGGL(main_kernel, dim3(64, 64), dim3(512), 0, stream,
                     Txp, Ty, W2s, b2f, W3f, b3f, out);
}

// Round 3
// 229.980 us; speedup vs baseline: 1.2660x; 1.0512x over previous
//
#include <hip/hip_runtime.h>
#include <stdint.h>

// ---------------------------------------------------------------------------
// NIVR: coord-MLP over 512x512 grid.
//   pre0_kernel: time branch once -> tvec[512].
//   pre1_kernel: posenc tables Txp (=Tx+tvec), Ty; W2f -> bf16 W2s.
//   main: h1 = relu(Txp[x]+Ty[y]); layer2 via MFMA bf16 16x16x32 (swapped
//         operands => acc holds h2^T); fused layer3 epilogue. Output [3][N].
//
// R12 vs R11: counters showed 4 pipes balanced at 33-37% (matrix 131k,
// DS 135k, L2 146k, VALU 139k cyc/CU vs 396k wall) with nothing saturated
// => convoy: all 16 waves/CU phase-locked by the barrier + identical code,
// so DS/VMEM see 64KB/CU bursts (transient 85% saturation -> latency
// balloons -> all waves' lgkmcnt block together) alternating with
// matrix-only bursts. R12 decorrelates:
//  - wave-staggered K-loop: wave w starts at step kk=(ks+2w)&15 (legal:
//    acc order-independent, A fully resident after the one barrier).
//    kofs in SGPR via readfirstlane => per-step wrap is scalar math.
//  - s_setprio(1) around the MFMA cluster (T5: pays only with the role
//    diversity the stagger creates).
// Live set unchanged: 64 acc + 32 breg + 16 a + ~16 misc = 128 => 2 blk/CU.
// ---------------------------------------------------------------------------

typedef short bf16x8 __attribute__((ext_vector_type(8)));
typedef float f32x4 __attribute__((ext_vector_type(4)));

#define PI_F 3.14159265358979323846f
#define SIDE 512
#define NPIX (SIDE * SIDE)

__device__ __forceinline__ unsigned short f2bf(float f) {
  unsigned int u = __float_as_uint(f);
  u += 0x7fffu + ((u >> 16) & 1u);
  return (unsigned short)(u >> 16);
}

// ---------------------------------------------------------------------------
// pre0: ONE block, 512 threads. Time branch -> tvec[k] = b1f[k] + phi @ W1f
// rows 40..167.
// ---------------------------------------------------------------------------
__global__ void pre0_kernel(const float* __restrict__ W1p, const float* __restrict__ b1p,
                            const float* __restrict__ W2p, const float* __restrict__ b2p,
                            const float* __restrict__ W1f, const float* __restrict__ b1f,
                            const int* __restrict__ idx, float* __restrict__ tvec) {
  __shared__ float r_s[32];
  __shared__ float h_s[256];
  __shared__ float phi_s[128];
  const int t = threadIdx.x;
  if (t < 16) {
    float tt = (float)idx[0] / 300.0f;
    float ang = tt * ldexpf(PI_F, t);
    r_s[t] = sinf(ang);
    r_s[16 + t] = cosf(ang);
  }
  __syncthreads();
  if (t < 256) {
    float a = b1p[t];
#pragma unroll
    for (int i = 0; i < 32; ++i) a += r_s[i] * W1p[i * 256 + t];
    h_s[t] = fmaxf(a, 0.f);
  }
  __syncthreads();
  if (t < 128) {
    float a = b2p[t];
    for (int i = 0; i < 256; ++i) a += h_s[i] * W2p[i * 128 + t];
    phi_s[t] = a;
  }
  __syncthreads();
  {
    float tv = b1f[t];
    for (int p = 0; p < 128; ++p) tv += phi_s[p] * W1f[(40 + p) * 512 + t];
    tvec[t] = tv;
  }
}

// ---------------------------------------------------------------------------
// pre1: 1024 blocks x 512 threads.
//   blocks 0..511  : Txp[v][k] = tvec[k] + sum_l enc[l] W1f[l][k]
//                    Ty [v][k] =           sum_l enc[l] W1f[20+l][k]
//   blocks 512..1023: W2f -> bf16 frag-swizzled W2s (k-row = b-512)
// W2s layout: id = ks*16384 + nt*512 + q*128 + ni*8 + j  (shorts)
//   W2s[id] = bf16(W2f[ks*32 + q*8 + j][nt*16 + ni])
// ---------------------------------------------------------------------------
__global__ void pre1_kernel(const float* __restrict__ W1f, const float* __restrict__ W2f,
                            const float* __restrict__ tvec,
                            float* __restrict__ Txp, float* __restrict__ Ty,
                            unsigned short* __restrict__ W2s) {
  const int b = blockIdx.x;
  const int t = threadIdx.x;

  if (b >= 512) {
    const int k = b - 512, n = t;
    const int ks = k >> 5, q = (k >> 3) & 3, j = k & 7;
    const int nt = n >> 4, ni = n & 15;
    W2s[ks * 16384 + nt * 512 + q * 128 + ni * 8 + j] = f2bf(W2f[k * 512 + n]);
    return;
  }

  __shared__ float enc[20];
  if (t < 10) {
    float u = (float)b / 512.0f;
    float ang = u * ldexpf(PI_F, t);
    enc[t] = sinf(ang);
    enc[10 + t] = cosf(ang);
  }
  __syncthreads();
  {
    float ax = tvec[t], ay = 0.f;
#pragma unroll
    for (int l = 0; l < 20; ++l) {
      ax += enc[l] * W1f[l * 512 + t];
      ay += enc[l] * W1f[(20 + l) * 512 + t];
    }
    Txp[b * 512 + t] = ax;
    Ty[b * 512 + t] = ay;
  }
}

// ---------------------------------------------------------------------------
// Main fused kernel. Block = 512 thr (8 waves), BM=64 (8x8 patch), BN=512,
// K=512 in 16 steps of 32. Wave w owns N-slice [w*64, w*64+64).
// A tile 64KB resident in LDS (filled once); B via depth-1 register prefetch.
// Wave w walks K starting at step 2w (stagger; acc is order-independent).
// MFMA operands swapped: acc[mt][nt][r] = h2[pix=mt*16+lr][col=w*64+nt*16+q*4+r]
// ---------------------------------------------------------------------------
__global__ __launch_bounds__(512, 4) void main_kernel(
    const float* __restrict__ Txp, const float* __restrict__ Ty,
    const unsigned short* __restrict__ W2s, const float* __restrict__ b2f,
    const float* __restrict__ W3f, const float* __restrict__ b3f,
    float* __restrict__ out) {
  __shared__ __attribute__((aligned(16))) unsigned short Ab[16 * 2048];  // 64KB
  __shared__ float part[8][64][3];                                       // 6KB

  const int t = threadIdx.x;
  const int w = t >> 6;            // wave id 0..7  (N-slice)
  const int lane = t & 63;
  const int q = lane >> 4;
  const int lr = lane & 15;
  const int x0 = blockIdx.x * 8, y0 = blockIdx.y * 8;

  // K-loop phase offset per wave (SGPR): wave w starts at K-step 2w.
  const int kofs = __builtin_amdgcn_readfirstlane((w * 2) & 15);

  // B: wave w owns nt-slots w*4..w*4+3; frag (ks,nt) at +ks*16384 + nt*512;
  // lane reads at +lane*8 (16B, coalesced 1KB/wave).
  const unsigned short* bptr = W2s + (w * 4) * 512 + lane * 8;

  // ---- B pipeline: depth 1 (2 buffers). breg[ks&1] used at loop pos ks. ----
  bf16x8 breg[2][4];
#pragma unroll
  for (int nt = 0; nt < 4; ++nt)
    breg[0][nt] = *(const bf16x8*)(bptr + kofs * 16384 + nt * 512);

  // ---- A fill (once): thread (p = t>>3, s = t&7) covers pixel p,
  // k = ks*32 + s*4..+3; frag slot abase, conflict-free (R5-verified).
  // bf16 conversion via packed v_cvt_pk_bf16_f32 (RNE).
  {
    const int p = t >> 3, s = t & 7;
    const int xi = x0 + (p >> 3), yi = y0 + (p & 7);
    const float* txp = Txp + xi * 512 + s * 4;
    const float* typ = Ty + yi * 512 + s * 4;
    const int abase = (((p >> 4) * 4 + (s >> 1)) * 16 + (p & 15)) * 8 + (s & 1) * 4;
#pragma unroll
    for (int ks = 0; ks < 16; ++ks) {
      float4 a = *(const float4*)(txp + ks * 32);
      float4 b = *(const float4*)(typ + ks * 32);
      float v0 = fmaxf(a.x + b.x, 0.f);
      float v1 = fmaxf(a.y + b.y, 0.f);
      float v2 = fmaxf(a.z + b.z, 0.f);
      float v3 = fmaxf(a.w + b.w, 0.f);
      uint2 pk;
      asm("v_cvt_pk_bf16_f32 %0, %1, %2" : "=v"(pk.x) : "v"(v0), "v"(v1));
      asm("v_cvt_pk_bf16_f32 %0, %1, %2" : "=v"(pk.y) : "v"(v2), "v"(v3));
      *(uint2*)&Ab[ks * 2048 + abase] = pk;
    }
  }

  f32x4 acc[4][4];
#pragma unroll
  for (int i = 0; i < 4; ++i)
#pragma unroll
    for (int j2 = 0; j2 < 4; ++j2) acc[i][j2] = (f32x4){0.f, 0.f, 0.f, 0.f};

  __syncthreads();  // publishes A; the only barrier before the epilogue

  // ---- K-loop, fully unrolled, no barriers; wave-staggered start ----
#pragma unroll
  for (int ks = 0; ks < 16; ++ks) {
    const int kk = (ks + kofs) & 15;   // this wave's K-step this iteration
    // B loads for loop pos ks+1 (K-step kk+1), issued before this step's MFMAs
    if (ks + 1 < 16) {
      const int kn = (kk + 1) & 15;
#pragma unroll
      for (int nt = 0; nt < 4; ++nt)
        breg[(ks + 1) & 1][nt] =
            *(const bf16x8*)(bptr + kn * 16384 + nt * 512);
    }
    // A-frags for K-step kk: 4 ds_read_b128 sharing one vaddr (+imm offsets)
    const unsigned short* arow = &Ab[kk * 2048 + lane * 8];
    bf16x8 a0 = *(const bf16x8*)&arow[0 * 512];
    bf16x8 a1 = *(const bf16x8*)&arow[1 * 512];
    bf16x8 a2 = *(const bf16x8*)&arow[2 * 512];
    bf16x8 a3 = *(const bf16x8*)&arow[3 * 512];
    // MFMAs for K-step kk -- OPERANDS SWAPPED: D = W2slice^T x h1slice^T.
    __builtin_amdgcn_s_setprio(1);
#pragma unroll
    for (int nt = 0; nt < 4; ++nt) {
      acc[0][nt] = __builtin_amdgcn_mfma_f32_16x16x32_bf16(
          breg[ks & 1][nt], a0, acc[0][nt], 0, 0, 0);
      acc[1][nt] = __builtin_amdgcn_mfma_f32_16x16x32_bf16(
          breg[ks & 1][nt], a1, acc[1][nt], 0, 0, 0);
      acc[2][nt] = __builtin_amdgcn_mfma_f32_16x16x32_bf16(
          breg[ks & 1][nt], a2, acc[2][nt], 0, 0, 0);
      acc[3][nt] = __builtin_amdgcn_mfma_f32_16x16x32_bf16(
          breg[ks & 1][nt], a3, acc[3][nt], 0, 0, 0);
    }
    __builtin_amdgcn_s_setprio(0);
  }

  // ---- epilogue: h2 = relu(acc + b2f); rgb partial = h2 @ W3f.
  // Layer-3 k-dim (col) lives on (q,r) in-register; streamed per-nt to keep
  // peak register pressure ~96. Reduce over q via shfl_xor 16,32. ----
  {
    float p3[4][3];
#pragma unroll
    for (int mt = 0; mt < 4; ++mt) {
      p3[mt][0] = 0.f; p3[mt][1] = 0.f; p3[mt][2] = 0.f;
    }
#pragma unroll
    for (int nt = 0; nt < 4; ++nt) {
      const int k0 = w * 64 + nt * 16 + q * 4;
      float4 bv = *(const float4*)&b2f[k0];
      float bb[4] = {bv.x, bv.y, bv.z, bv.w};
      float4 u0 = *(const float4*)&W3f[k0 * 3 + 0];
      float4 u1 = *(const float4*)&W3f[k0 * 3 + 4];
      float4 u2 = *(const float4*)&W3f[k0 * 3 + 8];
      float wv[4][3];
      wv[0][0] = u0.x; wv[0][1] = u0.y; wv[0][2] = u0.z;
      wv[1][0] = u0.w; wv[1][1] = u1.x; wv[1][2] = u1.y;
      wv[2][0] = u1.z; wv[2][1] = u1.w; wv[2][2] = u2.x;
      wv[3][0] = u2.y; wv[3][1] = u2.z; wv[3][2] = u2.w;
#pragma unroll
      for (int mt = 0; mt < 4; ++mt)
#pragma unroll
        for (int r = 0; r < 4; ++r) {
          float h2 = fmaxf(acc[mt][nt][r] + bb[r], 0.f);
          p3[mt][0] += h2 * wv[r][0];
          p3[mt][1] += h2 * wv[r][1];
          p3[mt][2] += h2 * wv[r][2];
        }
    }
    // reduce partial over q (lanes l, l^16, l^32, l^48)
#pragma unroll
    for (int d = 16; d < 64; d <<= 1)
#pragma unroll
      for (int mt = 0; mt < 4; ++mt)
#pragma unroll
        for (int cc = 0; cc < 3; ++cc)
          p3[mt][cc] += __shfl_xor(p3[mt][cc], d, 64);
    if (q < 3) {
#pragma unroll
      for (int mt = 0; mt < 4; ++mt) part[w][mt * 16 + lr][q] = p3[mt][q];
    }
  }
  __syncthreads();
  if (t < 192) {
    const int c = t >> 6, mm = t & 63;
    float sum = b3f[c];
#pragma unroll
    for (int ww = 0; ww < 8; ++ww) sum += part[ww][mm][c];
    const int n = (x0 + (mm >> 3)) * 512 + (y0 + (mm & 7));
    out[c * NPIX + n] = sum;
  }
}

// ---------------------------------------------------------------------------
// Inputs: 0 coords (unused), 1 W1p, 2 b1p, 3 W2p, 4 b2p, 5 W1f, 6 b1f,
//         7 W2f, 8 b2f, 9 W3f, 10 b3f, 11 idx
// ---------------------------------------------------------------------------
extern "C" void kernel_launch(void* const* d_in, const int* in_sizes, int n_in,
                              void* d_out, int out_size, void* d_ws, size_t ws_size,
                              hipStream_t stream) {
  const float* W1p = (const float*)d_in[1];
  const float* b1p = (const float*)d_in[2];
  const float* W2p = (const float*)d_in[3];
  const float* b2p = (const float*)d_in[4];
  const float* W1f = (const float*)d_in[5];
  const float* b1f = (const float*)d_in[6];
  const float* W2f = (const float*)d_in[7];
  const float* b2f = (const float*)d_in[8];
  const float* W3f = (const float*)d_in[9];
  const float* b3f = (const float*)d_in[10];
  const int* idx = (const int*)d_in[11];
  float* out = (float*)d_out;

  char* ws = (char*)d_ws;
  float* Txp = (float*)ws;                                   // 1 MB
  float* Ty = (float*)(ws + (1u << 20));                     // 1 MB
  unsigned short* W2s = (unsigned short*)(ws + (2u << 20));  // 512 KB
  float* tvec = (float*)(ws + (2u << 20) + (512u << 10));    // 2 KB

  hipLaunchKernelGGL(pre0_kernel, dim3(1), dim3(512), 0, stream,
                     W1p, b1p, W2p, b2p, W1f, b1f, idx, tvec);
  hipLaunchKernelGGL(pre1_kernel, dim3(1024), dim3(512), 0, stream,
                     W1f, W2f, tvec, Txp, Ty, W2s);
  hipLaunchKernelGGL(main_kernel, dim3(64, 64), dim3(512), 0, stream,
                     Txp, Ty, W2s, b2f, W3f, b3f, out);
}